// Round 4
// baseline (366.954 us; speedup 1.0000x reference)
//
#include <hip/hip_runtime.h>
#include <stdint.h>

typedef unsigned short u16;
typedef __attribute__((ext_vector_type(8))) short s16x8;   // 8 bf16 in 4 VGPRs
typedef __attribute__((ext_vector_type(4))) float f32x4;   // MFMA accumulator
typedef __attribute__((ext_vector_type(4))) unsigned uint4v;

#define NEXP 8
#define HD 1024
#define DFF 4096
#define BM 128
#define BN 128
#define BK 32
// Bs image layout: [d=n&1][kbg=0..3][nb=0..63][8 u16]; kbg stride padded to 520 u16
#define BS_KSTR 520
#define BS_DSTR (4 * BS_KSTR)
#define BS_TOT  (2 * BS_DSTR)

__device__ __forceinline__ u16 f2bf(float f) {
  union { float f; unsigned u; } c; c.f = f;
  unsigned r = c.u + 0x7fffu + ((c.u >> 16) & 1u);   // RNE
  return (u16)(r >> 16);
}

__device__ __forceinline__ unsigned cvtpk(float a, float b) {
  unsigned r;
  asm("v_cvt_pk_bf16_f32 %0, %1, %2" : "=v"(r) : "v"(a), "v"(b));
  return r;   // lo = bf16(a), hi = bf16(b)
}

__device__ __forceinline__ void gload_lds16(const void* g, const void* l) {
  __builtin_amdgcn_global_load_lds(
      (const __attribute__((address_space(1))) unsigned int*)(uintptr_t)g,
      (__attribute__((address_space(3))) unsigned int*)(unsigned)(uintptr_t)l,
      16, 0, 0);
}

__global__ __launch_bounds__(64) void zero_k(int* counts) {
  if (threadIdx.x < NEXP) counts[threadIdx.x] = 0;
}

__global__ __launch_bounds__(64) void router_k(const float* __restrict__ x,
    const float* __restrict__ Wr, const float* __restrict__ br,
    int* __restrict__ counts, int* __restrict__ tok_exp, float* __restrict__ tok_gate) {
  const int t = blockIdx.x, l = threadIdx.x;
  const float* xr = x + (size_t)t * HD;
  float acc[NEXP];
#pragma unroll
  for (int j = 0; j < NEXP; ++j) acc[j] = 0.f;
  for (int h = l; h < HD; h += 64) {
    float xv = xr[h];
    const float4* w4 = (const float4*)(Wr + (size_t)h * NEXP);
    float4 a = w4[0], b = w4[1];
    acc[0] += xv * a.x; acc[1] += xv * a.y; acc[2] += xv * a.z; acc[3] += xv * a.w;
    acc[4] += xv * b.x; acc[5] += xv * b.y; acc[6] += xv * b.z; acc[7] += xv * b.w;
  }
#pragma unroll
  for (int j = 0; j < NEXP; ++j)
#pragma unroll
    for (int off = 32; off > 0; off >>= 1) acc[j] += __shfl_xor(acc[j], off);
  if (l == 0) {
    float lg[NEXP];
    float best = acc[0] + br[0]; int bi = 0;
    lg[0] = best;
#pragma unroll
    for (int j = 1; j < NEXP; ++j) {
      lg[j] = acc[j] + br[j];
      if (lg[j] > best) { best = lg[j]; bi = j; }
    }
    float s = 0.f;
#pragma unroll
    for (int j = 0; j < NEXP; ++j) s += expf(lg[j] - best);
    tok_exp[t] = bi;
    tok_gate[t] = 1.0f / s;
    atomicAdd(&counts[bi], 1);
  }
}

__global__ __launch_bounds__(64) void scan_k(const int* __restrict__ counts,
    int* __restrict__ seg, int* __restrict__ cursor,
    int* __restrict__ ntile, int* __restrict__ tile_e, int* __restrict__ tile_m) {
  if (threadIdx.x == 0) {
    int s = 0, nt = 0;
#pragma unroll
    for (int e = 0; e < NEXP; ++e) {
      seg[e] = s; cursor[e] = s;
      int c = counts[e];
      for (int m = 0; m < c; m += BM) { tile_e[nt] = e; tile_m[nt] = m; ++nt; }
      s += c;
    }
    seg[NEXP] = s;
    ntile[0] = nt;
  }
}

__global__ __launch_bounds__(64) void gather_k(const float* __restrict__ x,
    const int* __restrict__ tok_exp, const float* __restrict__ tok_gate,
    int* __restrict__ cursor, int* __restrict__ perm, float* __restrict__ gatep,
    u16* __restrict__ Xg) {
  const int t = blockIdx.x, l = threadIdx.x;
  int pos = 0;
  if (l == 0) {
    int e = tok_exp[t];
    pos = atomicAdd(&cursor[e], 1);
    perm[pos] = t;
    gatep[pos] = tok_gate[t];
  }
  pos = __shfl(pos, 0);
  const float4* xr = (const float4*)(x + (size_t)t * HD);
  ushort4* dst = (ushort4*)(Xg + (size_t)pos * HD);
#pragma unroll
  for (int i = 0; i < HD / 4 / 64; ++i) {
    float4 v = xr[l + i * 64];
    ushort4 o;
    o.x = f2bf(v.x); o.y = f2bf(v.y); o.z = f2bf(v.z); o.w = f2bf(v.w);
    dst[l + i * 64] = o;
  }
}

// Grouped GEMM, depth-2 counted-vmcnt pipeline on BOTH A (LDS) and B (regs).
// A: [T][KD] bf16 (permuted rows). W: [E][KD][ND] f32 (cvt_pk on the fly).
// As LDS layout: [g=k/8][row][8 u16] (k-group-major) -> conflict-free b128 frag reads;
// gload_lds dest stays linear, global SOURCE is permuted per-lane (T21).
// EPI 0: H1out = bf16(relu(acc+bias)).
// EPI 1: Yout[perm[row]] (+)= (acc [+bias if ks==0]) * gate  (atomic when KSPLIT>1)
template <int KD, int ND, int EPI, int KSPLIT>
__global__ __launch_bounds__(256) void ffn_gemm(
    const u16* __restrict__ A, const float* __restrict__ W,
    const float* __restrict__ bias, const int* __restrict__ seg,
    const int* __restrict__ ntile, const int* __restrict__ tile_e,
    const int* __restrict__ tile_m,
    u16* __restrict__ H1out, float* __restrict__ Yout,
    const int* __restrict__ perm, const float* __restrict__ gatep) {
  const int ti = blockIdx.y;
  if (ti >= ntile[0]) return;
  const int e  = tile_e[ti];
  const int m0 = tile_m[ti];
  const int ks = blockIdx.z;
  const int s0 = seg[e];
  const int cnt = seg[e + 1] - s0;
  const int n0 = blockIdx.x * BN;
  constexpr int NT = (KD / KSPLIT) / BK;
  static_assert(NT >= 4 && (NT & 1) == 0, "pipeline needs even NT >= 4");
  const int kbase = ks * (KD / KSPLIT);

  __shared__ __align__(16) u16 As[3][BM * BK];   // 3 x 8KB, [g][row][8] images
  __shared__ __align__(16) u16 Bs[2][BS_TOT];

  const int t = threadIdx.x;
  const int l = t & 63, w = t >> 6;              // 4 waves
  const int wr = w >> 1, wc = w & 1;

  const f32x4 fzero = {0.f, 0.f, 0.f, 0.f};
  f32x4 acc[4][4];
#pragma unroll
  for (int i = 0; i < 4; ++i)
#pragma unroll
    for (int j = 0; j < 4; ++j) acc[i][j] = fzero;

  // A staging sources: chunk c in {w, w+4}; slot s = c*64+l -> g = s>>7, row = s&127.
  // lane loads A[row], k-elems [g*8, g*8+8) => LDS linear pos == [g][row][8] image.
  const u16 *asrc0, *asrc1;
  {
    int c0 = w, c1 = w + 4;
    int g0 = c0 >> 1, r0 = (c0 & 1) * 64 + l;
    int g1 = c1 >> 1, r1 = (c1 & 1) * 64 + l;
    int rg0 = m0 + r0; if (rg0 >= cnt) rg0 = cnt - 1;
    int rg1 = m0 + r1; if (rg1 >= cnt) rg1 = cnt - 1;
    asrc0 = A + (size_t)(s0 + rg0) * KD + kbase + g0 * 8;
    asrc1 = A + (size_t)(s0 + rg1) * KD + kbase + g1 * 8;
  }
  // B staging: thread covers rows {2nb, 2nb+1} x k [kbg*8, kbg*8+8)
  const int nb = t & 63, kbg = t >> 6;
  const float* bp0 = W + ((size_t)e * KD + kbase + kbg * 8) * ND + n0 + nb * 2;

  u16* pa0 = &As[0][0];
  u16* pa1 = &As[1][0];
  u16* pa2 = &As[2][0];

  float2 bv0[8], bv1[8];   // two B register sets (depth-2), static indexing only

#define STAGE_A(pa, tt) do { \
    gload_lds16(asrc0 + (size_t)(tt) * BK, (pa) + w * 512); \
    gload_lds16(asrc1 + (size_t)(tt) * BK, (pa) + 2048 + w * 512); \
  } while (0)

#define LOAD_B(dst, tt) do { \
    const float* bp_ = bp0 + (size_t)(tt) * BK * ND; \
    _Pragma("unroll") for (int j_ = 0; j_ < 8; ++j_) dst[j_] = *(const float2*)(bp_ + (size_t)j_ * ND); \
  } while (0)

#define WRITE_B(src, par) do { \
    uint4v q0_, q1_; \
    _Pragma("unroll") for (int j_ = 0; j_ < 4; ++j_) { \
      q0_[j_] = cvtpk(src[2 * j_].x, src[2 * j_ + 1].x); \
      q1_[j_] = cvtpk(src[2 * j_].y, src[2 * j_ + 1].y); } \
    *(uint4v*)&Bs[par][kbg * BS_KSTR + nb * 8] = q0_; \
    *(uint4v*)&Bs[par][BS_DSTR + kbg * BS_KSTR + nb * 8] = q1_; \
  } while (0)

#define COMPUTE(pa, par) do { \
    s16x8 af_[4], bf_[4]; \
    _Pragma("unroll") for (int mi_ = 0; mi_ < 4; ++mi_) \
      af_[mi_] = *(const s16x8*)&(pa)[(l >> 4) * 1024 + (wr * 64 + mi_ * 16 + (l & 15)) * 8]; \
    _Pragma("unroll") for (int ni_ = 0; ni_ < 4; ++ni_) { \
      int n_ = wc * 64 + ni_ * 16 + (l & 15); \
      bf_[ni_] = *(const s16x8*)&Bs[par][(n_ & 1) * BS_DSTR + (l >> 4) * BS_KSTR + (n_ >> 1) * 8]; \
    } \
    _Pragma("unroll") for (int mi_ = 0; mi_ < 4; ++mi_) \
      _Pragma("unroll") for (int ni_ = 0; ni_ < 4; ++ni_) \
        acc[mi_][ni_] = __builtin_amdgcn_mfma_f32_16x16x32_bf16(af_[mi_], bf_[ni_], acc[mi_][ni_], 0, 0, 0); \
  } while (0)

#define ROTATE_A() do { u16* tmp_ = pa0; pa0 = pa1; pa1 = pa2; pa2 = tmp_; } while (0)

  // ---- prologue: issue B(0),A(0),B(1),A(1); wait oldest 10 (B0+A0); B1+A1 stay in flight
  LOAD_B(bv0, 0);
  STAGE_A(pa0, 0);
  LOAD_B(bv1, 1);
  STAGE_A(pa1, 1);
  asm volatile("s_waitcnt vmcnt(10)" ::: "memory");
  __builtin_amdgcn_sched_barrier(0);
  WRITE_B(bv0, 0);
  asm volatile("s_waitcnt lgkmcnt(0)" ::: "memory");
  __builtin_amdgcn_s_barrier();
  __builtin_amdgcn_sched_barrier(0);

  // ---- steady state (unrolled x2 for static regset parity):
  // iter tt: issue B(tt+2)+A(tt+2); compute tile tt; wait vmcnt(10) => B(tt+1)+A(tt+1)
  // landed (issued one full iteration ago); write B(tt+1) to LDS; barrier.
  for (int uu = 0; uu < NT - 2; uu += 2) {
    // tt = uu (even): B(uu+2)->set0, compute Bs[0], write B(uu+1) from set1 -> Bs[1]
    LOAD_B(bv0, uu + 2);
    STAGE_A(pa2, uu + 2);
    COMPUTE(pa0, 0);
    asm volatile("s_waitcnt vmcnt(10)" ::: "memory");
    __builtin_amdgcn_sched_barrier(0);
    WRITE_B(bv1, 1);
    asm volatile("s_waitcnt lgkmcnt(0)" ::: "memory");
    __builtin_amdgcn_s_barrier();
    __builtin_amdgcn_sched_barrier(0);
    ROTATE_A();
    // tt = uu+1 (odd): B(uu+3)->set1, compute Bs[1], write B(uu+2) from set0 -> Bs[0]
    LOAD_B(bv1, uu + 3);
    STAGE_A(pa2, uu + 3);
    COMPUTE(pa0, 1);
    asm volatile("s_waitcnt vmcnt(10)" ::: "memory");
    __builtin_amdgcn_sched_barrier(0);
    WRITE_B(bv0, 0);
    asm volatile("s_waitcnt lgkmcnt(0)" ::: "memory");
    __builtin_amdgcn_s_barrier();
    __builtin_amdgcn_sched_barrier(0);
    ROTATE_A();
  }
  // tt = NT-2 (even): compute Bs[0]; drain; write B(NT-1) from set1 -> Bs[1]
  COMPUTE(pa0, 0);
  asm volatile("s_waitcnt vmcnt(0)" ::: "memory");
  __builtin_amdgcn_sched_barrier(0);
  WRITE_B(bv1, 1);
  asm volatile("s_waitcnt lgkmcnt(0)" ::: "memory");
  __builtin_amdgcn_s_barrier();
  __builtin_amdgcn_sched_barrier(0);
  ROTATE_A();
  // tt = NT-1 (odd)
  COMPUTE(pa0, 1);

#undef STAGE_A
#undef LOAD_B
#undef WRITE_B
#undef COMPUTE
#undef ROTATE_A

  // epilogue: C/D frag map col=lane&15, row=(lane>>4)*4+reg  [m89/m91]
  const int lr = (l >> 4) * 4;
  const int lc = l & 15;
  float bv2[4];
#pragma unroll
  for (int ni = 0; ni < 4; ++ni)
    bv2[ni] = bias[(size_t)e * ND + n0 + wc * 64 + ni * 16 + lc];

  if constexpr (EPI == 0) {
#pragma unroll
    for (int mi = 0; mi < 4; ++mi) {
#pragma unroll
      for (int r = 0; r < 4; ++r) {
        int row = m0 + wr * 64 + mi * 16 + lr + r;
        if (row < cnt) {
          u16* hrow = H1out + (size_t)(s0 + row) * ND + n0 + wc * 64;
#pragma unroll
          for (int ni = 0; ni < 4; ++ni) {
            float v = acc[mi][ni][r] + bv2[ni];
            v = v > 0.f ? v : 0.f;
            hrow[ni * 16 + lc] = f2bf(v);
          }
        }
      }
    }
  } else {
#pragma unroll
    for (int mi = 0; mi < 4; ++mi) {
#pragma unroll
      for (int r = 0; r < 4; ++r) {
        int row = m0 + wr * 64 + mi * 16 + lr + r;
        if (row < cnt) {
          int tok = perm[s0 + row];
          float g = gatep[s0 + row];
          float* orow = Yout + (size_t)tok * ND + n0 + wc * 64;
#pragma unroll
          for (int ni = 0; ni < 4; ++ni) {
            float v = acc[mi][ni][r];
            if (KSPLIT == 1 || ks == 0) v += bv2[ni];
            v *= g;
            if constexpr (KSPLIT == 1) orow[ni * 16 + lc] = v;
            else atomicAdd(&orow[ni * 16 + lc], v);
          }
        }
      }
    }
  }
}

extern "C" void kernel_launch(void* const* d_in, const int* in_sizes, int n_in,
                              void* d_out, int out_size, void* d_ws, size_t ws_size,
                              hipStream_t stream) {
  const float* x  = (const float*)d_in[0];
  const float* Wr = (const float*)d_in[1];
  const float* br = (const float*)d_in[2];
  const float* W1 = (const float*)d_in[3];
  const float* b1 = (const float*)d_in[4];
  const float* W2 = (const float*)d_in[5];
  const float* b2 = (const float*)d_in[6];
  float* out = (float*)d_out;

  const int T = in_sizes[0] / HD;   // 4096 tokens
  char* ws = (char*)d_ws;
  int*   counts   = (int*)(ws + 0);
  int*   cursor   = (int*)(ws + 64);
  int*   seg      = (int*)(ws + 128);
  int*   ntile    = (int*)(ws + 192);
  int*   tile_e   = (int*)(ws + 256);
  int*   tile_m   = (int*)(ws + 512);
  int*   tok_exp  = (int*)(ws + 1024);
  float* tok_gate = (float*)(ws + 1024 + 4 * (size_t)T);
  int*   perm     = (int*)(ws + 1024 + 8 * (size_t)T);
  float* gatep    = (float*)(ws + 1024 + 12 * (size_t)T);
  u16*   Xg       = (u16*)(ws + 1024 + 16 * (size_t)T);                       // T*HD bf16
  u16*   H1       = (u16*)(ws + 1024 + 16 * (size_t)T + 2 * (size_t)T * HD);  // T*DFF bf16

  hipMemsetAsync(out, 0, (size_t)out_size * sizeof(float), stream);  // split-K accumulates
  hipLaunchKernelGGL(zero_k, dim3(1), dim3(64), 0, stream, counts);
  hipLaunchKernelGGL(router_k, dim3(T), dim3(64), 0, stream, x, Wr, br, counts, tok_exp, tok_gate);
  hipLaunchKernelGGL(scan_k, dim3(1), dim3(64), 0, stream, counts, seg, cursor, ntile, tile_e, tile_m);
  hipLaunchKernelGGL(gather_k, dim3(T), dim3(64), 0, stream, x, tok_exp, tok_gate, cursor, perm, gatep, Xg);
  const int maxtile = (T + BM - 1) / BM + NEXP - 1;   // 39: worst-case sum of per-expert ceils
  hipLaunchKernelGGL((ffn_gemm<HD, DFF, 0, 1>), dim3(DFF / BN, maxtile, 1), dim3(256), 0, stream,
                     Xg, W1, b1, seg, ntile, tile_e, tile_m, H1, nullptr, nullptr, nullptr);
  hipLaunchKernelGGL((ffn_gemm<DFF, HD, 1, 4>), dim3(HD / BN, maxtile, 4), dim3(256), 0, stream,
                     H1, W2, b2, seg, ntile, tile_e, tile_m, nullptr, out, perm, gatep);
}

// Round 5
// 343.735 us; speedup vs baseline: 1.0676x; 1.0676x over previous
//
#include <hip/hip_runtime.h>
#include <stdint.h>

typedef unsigned short u16;
typedef __attribute__((ext_vector_type(8))) short s16x8;   // 8 bf16 in 4 VGPRs
typedef __attribute__((ext_vector_type(4))) float f32x4;   // MFMA accumulator

#define NEXP 8
#define HD 1024
#define DFF 4096
#define BM 128
#define BN 128
#define BK 32

__device__ __forceinline__ u16 f2bf(float f) {
  union { float f; unsigned u; } c; c.f = f;
  unsigned r = c.u + 0x7fffu + ((c.u >> 16) & 1u);   // RNE
  return (u16)(r >> 16);
}

__device__ __forceinline__ void gload_lds16(const void* g, const void* l) {
  __builtin_amdgcn_global_load_lds(
      (const __attribute__((address_space(1))) unsigned int*)(uintptr_t)g,
      (__attribute__((address_space(3))) unsigned int*)(unsigned)(uintptr_t)l,
      16, 0, 0);
}

__global__ __launch_bounds__(64) void zero_k(int* counts) {
  if (threadIdx.x < NEXP) counts[threadIdx.x] = 0;
}

__global__ __launch_bounds__(64) void router_k(const float* __restrict__ x,
    const float* __restrict__ Wr, const float* __restrict__ br,
    int* __restrict__ counts, int* __restrict__ tok_exp, float* __restrict__ tok_gate) {
  const int t = blockIdx.x, l = threadIdx.x;
  const float* xr = x + (size_t)t * HD;
  float acc[NEXP];
#pragma unroll
  for (int j = 0; j < NEXP; ++j) acc[j] = 0.f;
  for (int h = l; h < HD; h += 64) {
    float xv = xr[h];
    const float4* w4 = (const float4*)(Wr + (size_t)h * NEXP);
    float4 a = w4[0], b = w4[1];
    acc[0] += xv * a.x; acc[1] += xv * a.y; acc[2] += xv * a.z; acc[3] += xv * a.w;
    acc[4] += xv * b.x; acc[5] += xv * b.y; acc[6] += xv * b.z; acc[7] += xv * b.w;
  }
#pragma unroll
  for (int j = 0; j < NEXP; ++j)
#pragma unroll
    for (int off = 32; off > 0; off >>= 1) acc[j] += __shfl_xor(acc[j], off);
  if (l == 0) {
    float lg[NEXP];
    float best = acc[0] + br[0]; int bi = 0;
    lg[0] = best;
#pragma unroll
    for (int j = 1; j < NEXP; ++j) {
      lg[j] = acc[j] + br[j];
      if (lg[j] > best) { best = lg[j]; bi = j; }
    }
    float s = 0.f;
#pragma unroll
    for (int j = 0; j < NEXP; ++j) s += expf(lg[j] - best);
    tok_exp[t] = bi;
    tok_gate[t] = 1.0f / s;
    atomicAdd(&counts[bi], 1);
  }
}

__global__ __launch_bounds__(64) void scan_k(const int* __restrict__ counts,
    int* __restrict__ seg, int* __restrict__ cursor,
    int* __restrict__ ntile, int* __restrict__ tile_e, int* __restrict__ tile_m) {
  if (threadIdx.x == 0) {
    int s = 0, nt = 0;
#pragma unroll
    for (int e = 0; e < NEXP; ++e) {
      seg[e] = s; cursor[e] = s;
      int c = counts[e];
      for (int m = 0; m < c; m += BM) { tile_e[nt] = e; tile_m[nt] = m; ++nt; }
      s += c;
    }
    seg[NEXP] = s;
    ntile[0] = nt;
  }
}

__global__ __launch_bounds__(64) void gather_k(const float* __restrict__ x,
    const int* __restrict__ tok_exp, const float* __restrict__ tok_gate,
    int* __restrict__ cursor, int* __restrict__ perm, float* __restrict__ gatep,
    u16* __restrict__ Xg) {
  const int t = blockIdx.x, l = threadIdx.x;
  int pos = 0;
  if (l == 0) {
    int e = tok_exp[t];
    pos = atomicAdd(&cursor[e], 1);
    perm[pos] = t;
    gatep[pos] = tok_gate[t];
  }
  pos = __shfl(pos, 0);
  const float4* xr = (const float4*)(x + (size_t)t * HD);
  ushort4* dst = (ushort4*)(Xg + (size_t)pos * HD);
#pragma unroll
  for (int i = 0; i < HD / 4 / 64; ++i) {
    float4 v = xr[l + i * 64];
    ushort4 o;
    o.x = f2bf(v.x); o.y = f2bf(v.y); o.z = f2bf(v.z); o.w = f2bf(v.w);
    dst[l + i * 64] = o;
  }
}

// Transpose+convert: W [E][K][N] f32 -> Wt [E][N][K] bf16.  64x64 tiles via LDS.
template <int K, int N>
__global__ __launch_bounds__(256) void convt_k(const float* __restrict__ W,
                                               u16* __restrict__ Wt) {
  __shared__ u16 T[64][72];   // pad 72: 16B-aligned rows, phase-2 reads contiguous
  const int e = blockIdx.y;
  const int k0 = (blockIdx.x % (K / 64)) * 64;
  const int n0 = (blockIdx.x / (K / 64)) * 64;
  const float* src = W + (size_t)e * K * N;
  u16* dst = Wt + (size_t)e * K * N;
  const int t = threadIdx.x;
  const int kk = t >> 4, c4 = (t & 15) * 4;
#pragma unroll
  for (int r = 0; r < 4; ++r) {
    float4 v = *(const float4*)(src + (size_t)(k0 + r * 16 + kk) * N + n0 + c4);
    T[c4 + 0][r * 16 + kk] = f2bf(v.x);
    T[c4 + 1][r * 16 + kk] = f2bf(v.y);
    T[c4 + 2][r * 16 + kk] = f2bf(v.z);
    T[c4 + 3][r * 16 + kk] = f2bf(v.w);
  }
  __syncthreads();
  const int c8 = (t & 7) * 8;
#pragma unroll
  for (int r = 0; r < 2; ++r) {
    int nn = r * 32 + (t >> 3);
    *(s16x8*)(dst + (size_t)(n0 + nn) * K + k0 + c8) = *(const s16x8*)&T[nn][c8];
  }
}

// m97-structure grouped GEMM: both operands bf16, staged via global_load_lds w=16,
// plain two-barrier loop, compiler-scheduled. A:[T][KD] (permuted rows), Bt:[E][ND][KD].
// EPI 0: H1out = bf16(relu(acc+bias)).
// EPI 1: Yout[perm[row]] (+)= (acc [+bias if ks==0]) * gate  (atomic when KSPLIT>1)
template <int KD, int ND, int EPI, int KSPLIT>
__global__ __launch_bounds__(256) void ffn_gemm(
    const u16* __restrict__ A, const u16* __restrict__ Bt,
    const float* __restrict__ bias, const int* __restrict__ seg,
    const int* __restrict__ ntile, const int* __restrict__ tile_e,
    const int* __restrict__ tile_m,
    u16* __restrict__ H1out, float* __restrict__ Yout,
    const int* __restrict__ perm, const float* __restrict__ gatep) {
  const int ti = blockIdx.y;
  if (ti >= ntile[0]) return;
  const int e  = tile_e[ti];
  const int m0 = tile_m[ti];
  const int ks = blockIdx.z;
  const int s0 = seg[e];
  const int cnt = seg[e + 1] - s0;
  const int n0 = blockIdx.x * BN;
  constexpr int NT = (KD / KSPLIT) / BK;
  const int kbase = ks * (KD / KSPLIT);

  __shared__ __align__(16) u16 As[BM * BK];   // [128][32] linear
  __shared__ __align__(16) u16 Bs[BN * BK];   // [128][32] linear (Bt rows)

  const int t = threadIdx.x;
  const int l = t & 63, w = t >> 6;
  const int wr = w >> 1, wc = w & 1;

  const f32x4 fzero = {0.f, 0.f, 0.f, 0.f};
  f32x4 acc[4][4];
#pragma unroll
  for (int i = 0; i < 4; ++i)
#pragma unroll
    for (int j = 0; j < 4; ++j) acc[i][j] = fzero;

  // staging map (proven r1/r3): chunk i in {0,1}, idx = i*256+t, row = idx>>2,
  // k = (idx&3)*8, LDS dest = idx*16B (wave-uniform base + lane*16).
  const u16 *asrc0, *asrc1, *bsrc0, *bsrc1;
  {
    int row0 = t >> 2, k0c = (t & 3) * 8;
    int row1 = (256 + t) >> 2;
    int rg0 = m0 + row0; if (rg0 >= cnt) rg0 = cnt - 1;
    int rg1 = m0 + row1; if (rg1 >= cnt) rg1 = cnt - 1;
    asrc0 = A + (size_t)(s0 + rg0) * KD + kbase + k0c;
    asrc1 = A + (size_t)(s0 + rg1) * KD + kbase + k0c;
    const u16* bte = Bt + (size_t)e * ND * KD;
    bsrc0 = bte + (size_t)(n0 + row0) * KD + kbase + k0c;
    bsrc1 = bte + (size_t)(n0 + row1) * KD + kbase + k0c;
  }

  for (int tt = 0; tt < NT; ++tt) {
    __syncthreads();
    const size_t ko = (size_t)tt * BK;
    gload_lds16(asrc0 + ko, &As[w * 512]);
    gload_lds16(asrc1 + ko, &As[2048 + w * 512]);
    gload_lds16(bsrc0 + ko, &Bs[w * 512]);
    gload_lds16(bsrc1 + ko, &Bs[2048 + w * 512]);
    __syncthreads();
    s16x8 af[4], bfr[4];
#pragma unroll
    for (int mi = 0; mi < 4; ++mi)
      af[mi] = *(const s16x8*)&As[(wr * 64 + mi * 16 + (l & 15)) * BK + (l >> 4) * 8];
#pragma unroll
    for (int ni = 0; ni < 4; ++ni)
      bfr[ni] = *(const s16x8*)&Bs[(wc * 64 + ni * 16 + (l & 15)) * BK + (l >> 4) * 8];
#pragma unroll
    for (int mi = 0; mi < 4; ++mi)
#pragma unroll
      for (int ni = 0; ni < 4; ++ni)
        acc[mi][ni] = __builtin_amdgcn_mfma_f32_16x16x32_bf16(af[mi], bfr[ni], acc[mi][ni], 0, 0, 0);
  }

  // epilogue: C/D frag map col=lane&15, row=(lane>>4)*4+reg  [m89/m91]
  const int lr = (l >> 4) * 4;
  const int lc = l & 15;
  float bv2[4];
#pragma unroll
  for (int ni = 0; ni < 4; ++ni)
    bv2[ni] = bias[(size_t)e * ND + n0 + wc * 64 + ni * 16 + lc];

  if constexpr (EPI == 0) {
#pragma unroll
    for (int mi = 0; mi < 4; ++mi) {
#pragma unroll
      for (int r = 0; r < 4; ++r) {
        int row = m0 + wr * 64 + mi * 16 + lr + r;
        if (row < cnt) {
          u16* hrow = H1out + (size_t)(s0 + row) * ND + n0 + wc * 64;
#pragma unroll
          for (int ni = 0; ni < 4; ++ni) {
            float v = acc[mi][ni][r] + bv2[ni];
            v = v > 0.f ? v : 0.f;
            hrow[ni * 16 + lc] = f2bf(v);
          }
        }
      }
    }
  } else {
#pragma unroll
    for (int mi = 0; mi < 4; ++mi) {
#pragma unroll
      for (int r = 0; r < 4; ++r) {
        int row = m0 + wr * 64 + mi * 16 + lr + r;
        if (row < cnt) {
          int tok = perm[s0 + row];
          float g = gatep[s0 + row];
          float* orow = Yout + (size_t)tok * ND + n0 + wc * 64;
#pragma unroll
          for (int ni = 0; ni < 4; ++ni) {
            float v = acc[mi][ni][r];
            if (KSPLIT == 1 || ks == 0) v += bv2[ni];
            v *= g;
            if constexpr (KSPLIT == 1) orow[ni * 16 + lc] = v;
            else atomicAdd(&orow[ni * 16 + lc], v);
          }
        }
      }
    }
  }
}

extern "C" void kernel_launch(void* const* d_in, const int* in_sizes, int n_in,
                              void* d_out, int out_size, void* d_ws, size_t ws_size,
                              hipStream_t stream) {
  const float* x  = (const float*)d_in[0];
  const float* Wr = (const float*)d_in[1];
  const float* br = (const float*)d_in[2];
  const float* W1 = (const float*)d_in[3];
  const float* b1 = (const float*)d_in[4];
  const float* W2 = (const float*)d_in[5];
  const float* b2 = (const float*)d_in[6];
  float* out = (float*)d_out;

  const int T = in_sizes[0] / HD;   // 4096 tokens
  char* ws = (char*)d_ws;
  int*   counts   = (int*)(ws + 0);
  int*   cursor   = (int*)(ws + 64);
  int*   seg      = (int*)(ws + 128);
  int*   ntile    = (int*)(ws + 192);
  int*   tile_e   = (int*)(ws + 256);
  int*   tile_m   = (int*)(ws + 512);
  int*   tok_exp  = (int*)(ws + 1024);
  float* tok_gate = (float*)(ws + 1024 + 4 * (size_t)T);
  int*   perm     = (int*)(ws + 1024 + 8 * (size_t)T);
  float* gatep    = (float*)(ws + 1024 + 12 * (size_t)T);
  u16*   Xg       = (u16*)(ws + 1024 + 16 * (size_t)T);                       // T*HD bf16 (8MB)
  u16*   H1       = (u16*)(ws + 1024 + 16 * (size_t)T + 2 * (size_t)T * HD);  // T*DFF bf16 (32MB)
  size_t off2     = 1024 + 16 * (size_t)T + 2 * (size_t)T * HD + 2 * (size_t)T * DFF;
  u16*   W1t      = (u16*)(ws + off2);                                        // E*DFF*HD bf16 (64MB)
  u16*   W2t      = (u16*)(ws + off2 + 2 * (size_t)NEXP * HD * DFF);          // E*HD*DFF bf16 (64MB)

  hipMemsetAsync(out, 0, (size_t)out_size * sizeof(float), stream);  // split-K accumulates
  hipLaunchKernelGGL(zero_k, dim3(1), dim3(64), 0, stream, counts);
  hipLaunchKernelGGL(router_k, dim3(T), dim3(64), 0, stream, x, Wr, br, counts, tok_exp, tok_gate);
  hipLaunchKernelGGL(scan_k, dim3(1), dim3(64), 0, stream, counts, seg, cursor, ntile, tile_e, tile_m);
  hipLaunchKernelGGL(gather_k, dim3(T), dim3(64), 0, stream, x, tok_exp, tok_gate, cursor, perm, gatep, Xg);
  // W1 [E][HD][DFF] -> W1t [E][DFF][HD];  W2 [E][DFF][HD] -> W2t [E][HD][DFF]
  hipLaunchKernelGGL((convt_k<HD, DFF>), dim3((HD / 64) * (DFF / 64), NEXP), dim3(256), 0, stream, W1, W1t);
  hipLaunchKernelGGL((convt_k<DFF, HD>), dim3((DFF / 64) * (HD / 64), NEXP), dim3(256), 0, stream, W2, W2t);
  const int maxtile = (T + BM - 1) / BM + NEXP - 1;   // 39: worst-case sum of per-expert ceils
  hipLaunchKernelGGL((ffn_gemm<HD, DFF, 0, 1>), dim3(DFF / BN, maxtile, 1), dim3(256), 0, stream,
                     Xg, W1t, b1, seg, ntile, tile_e, tile_m, H1, nullptr, nullptr, nullptr);
  hipLaunchKernelGGL((ffn_gemm<DFF, HD, 1, 2>), dim3(HD / BN, maxtile, 2), dim3(256), 0, stream,
                     H1, W2t, b2, seg, ntile, tile_e, tile_m, nullptr, out, perm, gatep);
}

// Round 6
// 327.787 us; speedup vs baseline: 1.1195x; 1.0487x over previous
//
#include <hip/hip_runtime.h>
#include <stdint.h>

typedef unsigned short u16;
typedef __attribute__((ext_vector_type(8))) short s16x8;   // 8 bf16 in 4 VGPRs
typedef __attribute__((ext_vector_type(4))) float f32x4;   // MFMA accumulator

#define NEXP 8
#define HD 1024
#define DFF 4096
#define BM 128
#define BN 128
#define BK 64     // 128B rows: full-line coalescing; XOR-swizzled LDS (T21 both-sides)

__device__ __forceinline__ u16 f2bf(float f) {
  union { float f; unsigned u; } c; c.f = f;
  unsigned r = c.u + 0x7fffu + ((c.u >> 16) & 1u);   // RNE
  return (u16)(r >> 16);
}

__device__ __forceinline__ void gload_lds16(const void* g, const void* l) {
  __builtin_amdgcn_global_load_lds(
      (const __attribute__((address_space(1))) unsigned int*)(uintptr_t)g,
      (__attribute__((address_space(3))) unsigned int*)(unsigned)(uintptr_t)l,
      16, 0, 0);
}

__global__ __launch_bounds__(64) void zero_k(int* counts) {
  if (threadIdx.x < NEXP) counts[threadIdx.x] = 0;
}

__global__ __launch_bounds__(64) void router_k(const float* __restrict__ x,
    const float* __restrict__ Wr, const float* __restrict__ br,
    int* __restrict__ counts, int* __restrict__ tok_exp, float* __restrict__ tok_gate) {
  const int t = blockIdx.x, l = threadIdx.x;
  const float* xr = x + (size_t)t * HD;
  float acc[NEXP];
#pragma unroll
  for (int j = 0; j < NEXP; ++j) acc[j] = 0.f;
  for (int h = l; h < HD; h += 64) {
    float xv = xr[h];
    const float4* w4 = (const float4*)(Wr + (size_t)h * NEXP);
    float4 a = w4[0], b = w4[1];
    acc[0] += xv * a.x; acc[1] += xv * a.y; acc[2] += xv * a.z; acc[3] += xv * a.w;
    acc[4] += xv * b.x; acc[5] += xv * b.y; acc[6] += xv * b.z; acc[7] += xv * b.w;
  }
#pragma unroll
  for (int j = 0; j < NEXP; ++j)
#pragma unroll
    for (int off = 32; off > 0; off >>= 1) acc[j] += __shfl_xor(acc[j], off);
  if (l == 0) {
    float lg[NEXP];
    float best = acc[0] + br[0]; int bi = 0;
    lg[0] = best;
#pragma unroll
    for (int j = 1; j < NEXP; ++j) {
      lg[j] = acc[j] + br[j];
      if (lg[j] > best) { best = lg[j]; bi = j; }
    }
    float s = 0.f;
#pragma unroll
    for (int j = 0; j < NEXP; ++j) s += expf(lg[j] - best);
    tok_exp[t] = bi;
    tok_gate[t] = 1.0f / s;
    atomicAdd(&counts[bi], 1);
  }
}

__global__ __launch_bounds__(64) void scan_k(const int* __restrict__ counts,
    int* __restrict__ seg, int* __restrict__ cursor,
    int* __restrict__ ntile, int* __restrict__ tile_e, int* __restrict__ tile_m) {
  if (threadIdx.x == 0) {
    int s = 0, nt = 0;
#pragma unroll
    for (int e = 0; e < NEXP; ++e) {
      seg[e] = s; cursor[e] = s;
      int c = counts[e];
      for (int m = 0; m < c; m += BM) { tile_e[nt] = e; tile_m[nt] = m; ++nt; }
      s += c;
    }
    seg[NEXP] = s;
    ntile[0] = nt;
  }
}

__global__ __launch_bounds__(64) void gather_k(const float* __restrict__ x,
    const int* __restrict__ tok_exp, const float* __restrict__ tok_gate,
    int* __restrict__ cursor, int* __restrict__ perm, float* __restrict__ gatep,
    u16* __restrict__ Xg) {
  const int t = blockIdx.x, l = threadIdx.x;
  int pos = 0;
  if (l == 0) {
    int e = tok_exp[t];
    pos = atomicAdd(&cursor[e], 1);
    perm[pos] = t;
    gatep[pos] = tok_gate[t];
  }
  pos = __shfl(pos, 0);
  const float4* xr = (const float4*)(x + (size_t)t * HD);
  ushort4* dst = (ushort4*)(Xg + (size_t)pos * HD);
#pragma unroll
  for (int i = 0; i < HD / 4 / 64; ++i) {
    float4 v = xr[l + i * 64];
    ushort4 o;
    o.x = f2bf(v.x); o.y = f2bf(v.y); o.z = f2bf(v.z); o.w = f2bf(v.w);
    dst[l + i * 64] = o;
  }
}

// Transpose+convert: W [E][K][N] f32 -> Wt [E][N][K] bf16.  64x64 tiles via LDS.
template <int K, int N>
__global__ __launch_bounds__(256) void convt_k(const float* __restrict__ W,
                                               u16* __restrict__ Wt) {
  __shared__ u16 T[64][72];
  const int e = blockIdx.y;
  const int k0 = (blockIdx.x % (K / 64)) * 64;
  const int n0 = (blockIdx.x / (K / 64)) * 64;
  const float* src = W + (size_t)e * K * N;
  u16* dst = Wt + (size_t)e * K * N;
  const int t = threadIdx.x;
  const int kk = t >> 4, c4 = (t & 15) * 4;
#pragma unroll
  for (int r = 0; r < 4; ++r) {
    float4 v = *(const float4*)(src + (size_t)(k0 + r * 16 + kk) * N + n0 + c4);
    T[c4 + 0][r * 16 + kk] = f2bf(v.x);
    T[c4 + 1][r * 16 + kk] = f2bf(v.y);
    T[c4 + 2][r * 16 + kk] = f2bf(v.z);
    T[c4 + 3][r * 16 + kk] = f2bf(v.w);
  }
  __syncthreads();
  const int c8 = (t & 7) * 8;
#pragma unroll
  for (int r = 0; r < 2; ++r) {
    int nn = r * 32 + (t >> 3);
    *(s16x8*)(dst + (size_t)(n0 + nn) * K + k0 + c8) = *(const s16x8*)&T[nn][c8];
  }
}

// m97-structure grouped GEMM, BK=64 with T21 XOR-swizzled LDS (chunk ^= row&7):
// linear gload_lds dest, pre-swizzled global SOURCE, swizzled frag reads.
// A:[T][KD] bf16 (permuted rows), Bt:[E][ND][KD] bf16.
// EPI 0: H1out = bf16(relu(acc+bias)).   EPI 2: Pt[ks][row][n] = acc (f32, raw partial).
template <int KD, int ND, int EPI, int KSPLIT, bool SWZ>
__global__ __launch_bounds__(256, 4) void ffn_gemm(
    const u16* __restrict__ A, const u16* __restrict__ Bt,
    const float* __restrict__ bias, const int* __restrict__ seg,
    const int* __restrict__ ntile, const int* __restrict__ tile_e,
    const int* __restrict__ tile_m,
    u16* __restrict__ H1out, float* __restrict__ Pt) {
  int bx, by;
  if constexpr (SWZ) {   // XCD-chunked: XCD c gets N-tiles {4c..4c+3} for all M-tiles
    int flat = blockIdx.y * (ND / BN) + blockIdx.x;
    bx = (flat & 7) * 4 + ((flat >> 3) & 3);
    by = flat >> 5;
  } else { bx = blockIdx.x; by = blockIdx.y; }
  if (by >= ntile[0]) return;
  const int e  = tile_e[by];
  const int m0 = tile_m[by];
  const int ks = blockIdx.z;
  const int s0 = seg[e];
  const int cnt = seg[e + 1] - s0;
  const int n0 = bx * BN;
  constexpr int NT = (KD / KSPLIT) / BK;
  const int kbase = ks * (KD / KSPLIT);

  __shared__ __align__(16) u16 As[BM * BK];   // [128][64] row-major, XOR-swizzled content
  __shared__ __align__(16) u16 Bs[BN * BK];

  const int t = threadIdx.x;
  const int l = t & 63, w = t >> 6;
  const int wr = w >> 1, wc = w & 1;

  const f32x4 fzero = {0.f, 0.f, 0.f, 0.f};
  f32x4 acc[4][4];
#pragma unroll
  for (int i = 0; i < 4; ++i)
#pragma unroll
    for (int j = 0; j < 4; ++j) acc[i][j] = fzero;

  // Staging: chunk c covers rows [c*32, c*32+32); lane slot idx=c*256+t -> row=idx>>3,
  // 16B-subchunk sub=idx&7. LDS dest linear (idx*16B). Source k-offset pre-swizzled:
  // koff = (sub ^ (row&7)) * 8 elems  (involution; full row still covered -> coalesced).
  const int sub = t & 7, r8 = t >> 3;           // r8 in [0,32)
  const int koff = (sub ^ (r8 & 7)) * 8;
  int aoff[4], boff[4];
  const u16* bte = Bt + (size_t)e * ND * KD;
#pragma unroll
  for (int c = 0; c < 4; ++c) {
    int row = c * 32 + r8;
    int rg = m0 + row; if (rg >= cnt) rg = cnt - 1;
    aoff[c] = (s0 + rg) * KD + kbase + koff;
    boff[c] = (n0 + row) * KD + kbase + koff;
  }

  for (int tt = 0; tt < NT; ++tt) {
    __syncthreads();
    const int ko = tt * BK;
#pragma unroll
    for (int c = 0; c < 4; ++c)
      gload_lds16(A + (size_t)aoff[c] + ko, &As[(c * 256 + t) * 8]);
#pragma unroll
    for (int c = 0; c < 4; ++c)
      gload_lds16(bte + (size_t)boff[c] + ko, &Bs[(c * 256 + t) * 8]);
    __syncthreads();
#pragma unroll
    for (int s = 0; s < 2; ++s) {
      // frag read: chunk index (s*4 + l>>4) ^ (row&7), row&7 == l&7 here
      const int fo = ((s * 4 + (l >> 4)) ^ (l & 7)) * 8;
      s16x8 af[4], bfr[4];
#pragma unroll
      for (int mi = 0; mi < 4; ++mi)
        af[mi] = *(const s16x8*)&As[(wr * 64 + mi * 16 + (l & 15)) * BK + fo];
#pragma unroll
      for (int ni = 0; ni < 4; ++ni)
        bfr[ni] = *(const s16x8*)&Bs[(wc * 64 + ni * 16 + (l & 15)) * BK + fo];
#pragma unroll
      for (int mi = 0; mi < 4; ++mi)
#pragma unroll
        for (int ni = 0; ni < 4; ++ni)
          acc[mi][ni] = __builtin_amdgcn_mfma_f32_16x16x32_bf16(af[mi], bfr[ni], acc[mi][ni], 0, 0, 0);
    }
  }

  // epilogue: C/D frag map col=lane&15, row=(lane>>4)*4+reg  [m89/m91]
  const int lr = (l >> 4) * 4;
  const int lc = l & 15;

  if constexpr (EPI == 0) {
    float bv2[4];
#pragma unroll
    for (int ni = 0; ni < 4; ++ni)
      bv2[ni] = bias[(size_t)e * ND + n0 + wc * 64 + ni * 16 + lc];
#pragma unroll
    for (int mi = 0; mi < 4; ++mi) {
#pragma unroll
      for (int r = 0; r < 4; ++r) {
        int row = m0 + wr * 64 + mi * 16 + lr + r;
        if (row < cnt) {
          u16* hrow = H1out + (size_t)(s0 + row) * ND + n0 + wc * 64;
#pragma unroll
          for (int ni = 0; ni < 4; ++ni) {
            float v = acc[mi][ni][r] + bv2[ni];
            v = v > 0.f ? v : 0.f;
            hrow[ni * 16 + lc] = f2bf(v);
          }
        }
      }
    }
  } else {
    const int totT = seg[NEXP];
#pragma unroll
    for (int mi = 0; mi < 4; ++mi) {
#pragma unroll
      for (int r = 0; r < 4; ++r) {
        int row = m0 + wr * 64 + mi * 16 + lr + r;
        if (row < cnt) {
          float* prow = Pt + ((size_t)ks * totT + s0 + row) * ND + n0 + wc * 64;
#pragma unroll
          for (int ni = 0; ni < 4; ++ni)
            prow[ni * 16 + lc] = acc[mi][ni][r];
        }
      }
    }
  }
}

// out[perm[pos]] = gate[pos] * (b2[e] + sum_ks Pt[ks][pos][:])
__global__ __launch_bounds__(256) void reduce_k(const float* __restrict__ Pt,
    const float* __restrict__ b2, const int* __restrict__ perm,
    const float* __restrict__ gatep, const int* __restrict__ tok_exp,
    float* __restrict__ out) {
  const int pos = blockIdx.x;
  const int totT = gridDim.x;
  const int tok = perm[pos];
  const float g = gatep[pos];
  const int e = tok_exp[tok];
  const int h = threadIdx.x * 4;
  float4 s = *(const float4*)(Pt + ((size_t)0 * totT + pos) * HD + h);
#pragma unroll
  for (int k = 1; k < 4; ++k) {
    float4 p = *(const float4*)(Pt + ((size_t)k * totT + pos) * HD + h);
    s.x += p.x; s.y += p.y; s.z += p.z; s.w += p.w;
  }
  float4 b = *(const float4*)(b2 + (size_t)e * HD + h);
  float4 o;
  o.x = (s.x + b.x) * g; o.y = (s.y + b.y) * g;
  o.z = (s.z + b.z) * g; o.w = (s.w + b.w) * g;
  *(float4*)(out + (size_t)tok * HD + h) = o;
}

extern "C" void kernel_launch(void* const* d_in, const int* in_sizes, int n_in,
                              void* d_out, int out_size, void* d_ws, size_t ws_size,
                              hipStream_t stream) {
  const float* x  = (const float*)d_in[0];
  const float* Wr = (const float*)d_in[1];
  const float* br = (const float*)d_in[2];
  const float* W1 = (const float*)d_in[3];
  const float* b1 = (const float*)d_in[4];
  const float* W2 = (const float*)d_in[5];
  const float* b2 = (const float*)d_in[6];
  float* out = (float*)d_out;

  const int T = in_sizes[0] / HD;   // 4096 tokens
  char* ws = (char*)d_ws;
  int*   counts   = (int*)(ws + 0);
  int*   cursor   = (int*)(ws + 64);
  int*   seg      = (int*)(ws + 128);
  int*   ntile    = (int*)(ws + 192);
  int*   tile_e   = (int*)(ws + 256);
  int*   tile_m   = (int*)(ws + 512);
  int*   tok_exp  = (int*)(ws + 1024);
  float* tok_gate = (float*)(ws + 1024 + 4 * (size_t)T);
  int*   perm     = (int*)(ws + 1024 + 8 * (size_t)T);
  float* gatep    = (float*)(ws + 1024 + 12 * (size_t)T);
  u16*   Xg       = (u16*)(ws + 1024 + 16 * (size_t)T);                       // T*HD bf16 (8MB)
  u16*   H1       = (u16*)(ws + 1024 + 16 * (size_t)T + 2 * (size_t)T * HD);  // T*DFF bf16 (32MB)
  size_t off2     = 1024 + 16 * (size_t)T + 2 * (size_t)T * HD + 2 * (size_t)T * DFF;
  u16*   W1t      = (u16*)(ws + off2);                                        // E*DFF*HD bf16 (64MB)
  u16*   W2t      = (u16*)(ws + off2 + 2 * (size_t)NEXP * HD * DFF);          // E*HD*DFF bf16 (64MB)
  float* Pt       = (float*)W1t;   // GEMM2 split-K partials (4*T*HD f32 = 64MB) reuse W1t

  hipLaunchKernelGGL(zero_k, dim3(1), dim3(64), 0, stream, counts);
  hipLaunchKernelGGL(router_k, dim3(T), dim3(64), 0, stream, x, Wr, br, counts, tok_exp, tok_gate);
  hipLaunchKernelGGL(scan_k, dim3(1), dim3(64), 0, stream, counts, seg, cursor, ntile, tile_e, tile_m);
  hipLaunchKernelGGL(gather_k, dim3(T), dim3(64), 0, stream, x, tok_exp, tok_gate, cursor, perm, gatep, Xg);
  // W1 [E][HD][DFF] -> W1t [E][DFF][HD];  W2 [E][DFF][HD] -> W2t [E][HD][DFF]
  hipLaunchKernelGGL((convt_k<HD, DFF>), dim3((HD / 64) * (DFF / 64), NEXP), dim3(256), 0, stream, W1, W1t);
  hipLaunchKernelGGL((convt_k<DFF, HD>), dim3((DFF / 64) * (HD / 64), NEXP), dim3(256), 0, stream, W2, W2t);
  const int maxtile = (T + BM - 1) / BM + NEXP - 1;   // 39 worst case
  hipLaunchKernelGGL((ffn_gemm<HD, DFF, 0, 1, true>), dim3(DFF / BN, maxtile, 1), dim3(256), 0, stream,
                     Xg, W1t, b1, seg, ntile, tile_e, tile_m, H1, nullptr);
  hipLaunchKernelGGL((ffn_gemm<DFF, HD, 2, 4, false>), dim3(HD / BN, maxtile, 4), dim3(256), 0, stream,
                     H1, W2t, nullptr, seg, ntile, tile_e, tile_m, nullptr, Pt);
  hipLaunchKernelGGL(reduce_k, dim3(T), dim3(256), 0, stream, Pt, b2, perm, gatep, tok_exp, out);
}

// Round 7
// 308.594 us; speedup vs baseline: 1.1891x; 1.0622x over previous
//
#include <hip/hip_runtime.h>
#include <stdint.h>

typedef unsigned short u16;
typedef __attribute__((ext_vector_type(8))) short s16x8;   // 8 bf16 in 4 VGPRs
typedef __attribute__((ext_vector_type(4))) float f32x4;   // MFMA accumulator

#define NEXP 8
#define HD 1024
#define DFF 4096
#define BM 128
#define BN 128
#define BK 64     // 128B rows: full-line coalescing; XOR-swizzled LDS (T21 both-sides)

__device__ __forceinline__ u16 f2bf(float f) {
  union { float f; unsigned u; } c; c.f = f;
  unsigned r = c.u + 0x7fffu + ((c.u >> 16) & 1u);   // RNE
  return (u16)(r >> 16);
}

__device__ __forceinline__ void gload_lds16(const void* g, const void* l) {
  __builtin_amdgcn_global_load_lds(
      (const __attribute__((address_space(1))) unsigned int*)(uintptr_t)g,
      (__attribute__((address_space(3))) unsigned int*)(unsigned)(uintptr_t)l,
      16, 0, 0);
}

__global__ __launch_bounds__(64) void zero_k(int* counts) {
  if (threadIdx.x < NEXP) counts[threadIdx.x] = 0;
}

// 64x64 transpose+convert tile: W [K][N] f32 -> Wt [N][K] bf16 (one expert slice)
template <int K, int N>
__device__ __forceinline__ void convt_tile(const float* __restrict__ W,
    u16* __restrict__ Wt, int idx, u16 (*T)[72]) {
  const int e = idx >> 10;                       // tilesPerExpert = (K/64)*(N/64) = 1024
  const int ti = idx & 1023;
  const int k0 = (ti % (K / 64)) * 64;
  const int n0 = (ti / (K / 64)) * 64;
  const float* src = W + (size_t)e * K * N;
  u16* dst = Wt + (size_t)e * K * N;
  const int t = threadIdx.x;
  const int kk = t >> 4, c4 = (t & 15) * 4;
#pragma unroll
  for (int r = 0; r < 4; ++r) {
    float4 v = *(const float4*)(src + (size_t)(k0 + r * 16 + kk) * N + n0 + c4);
    T[c4 + 0][r * 16 + kk] = f2bf(v.x);
    T[c4 + 1][r * 16 + kk] = f2bf(v.y);
    T[c4 + 2][r * 16 + kk] = f2bf(v.z);
    T[c4 + 3][r * 16 + kk] = f2bf(v.w);
  }
  __syncthreads();
  const int c8 = (t & 7) * 8;
#pragma unroll
  for (int r = 0; r < 2; ++r) {
    int nn = r * 32 + (t >> 3);
    *(s16x8*)(dst + (size_t)(n0 + nn) * K + k0 + c8) = *(const s16x8*)&T[nn][c8];
  }
}

// Fused prep: router (wave per token) + W1 transpose + W2 transpose, one launch.
// All three are independent & memory-bound -> concurrent blocks share HBM BW.
__global__ __launch_bounds__(256) void prep_k(
    const float* __restrict__ x, const float* __restrict__ Wr,
    const float* __restrict__ br, int* __restrict__ counts,
    int* __restrict__ tok_exp, float* __restrict__ tok_gate,
    const float* __restrict__ W1, u16* __restrict__ W1t,
    const float* __restrict__ W2, u16* __restrict__ W2t, int T) {
  __shared__ u16 Tt[64][72];
  const int bid = blockIdx.x;
  const int NBR = T / 4;                                   // router blocks (4 tokens each)
  constexpr int NBC1 = (HD / 64) * (DFF / 64) * NEXP;      // 8192
  if (bid < NBR) {
    const int w = threadIdx.x >> 6, l = threadIdx.x & 63;
    const int t = bid * 4 + w;
    const float4* xr = (const float4*)(x + (size_t)t * HD);
    float acc[NEXP];
#pragma unroll
    for (int j = 0; j < NEXP; ++j) acc[j] = 0.f;
#pragma unroll
    for (int i = 0; i < 4; ++i) {
      float4 v = xr[l + i * 64];
      const int h = (l + i * 64) * 4;
      const float* w0 = Wr + (size_t)h * NEXP;
#pragma unroll
      for (int c = 0; c < 4; ++c) {
        float xv = (c == 0) ? v.x : (c == 1) ? v.y : (c == 2) ? v.z : v.w;
        const float4* wr4 = (const float4*)(w0 + c * NEXP);
        float4 a = wr4[0], b = wr4[1];
        acc[0] += xv * a.x; acc[1] += xv * a.y; acc[2] += xv * a.z; acc[3] += xv * a.w;
        acc[4] += xv * b.x; acc[5] += xv * b.y; acc[6] += xv * b.z; acc[7] += xv * b.w;
      }
    }
#pragma unroll
    for (int j = 0; j < NEXP; ++j)
#pragma unroll
      for (int off = 32; off > 0; off >>= 1) acc[j] += __shfl_xor(acc[j], off);
    if (l == 0) {
      float lg[NEXP];
      float best = acc[0] + br[0]; int bi = 0;
      lg[0] = best;
#pragma unroll
      for (int j = 1; j < NEXP; ++j) {
        lg[j] = acc[j] + br[j];
        if (lg[j] > best) { best = lg[j]; bi = j; }
      }
      float s = 0.f;
#pragma unroll
      for (int j = 0; j < NEXP; ++j) s += expf(lg[j] - best);
      tok_exp[t] = bi;
      tok_gate[t] = 1.0f / s;
      atomicAdd(&counts[bi], 1);
    }
  } else if (bid < NBR + NBC1) {
    convt_tile<HD, DFF>(W1, W1t, bid - NBR, Tt);           // W1 [E][HD][DFF] -> [E][DFF][HD]
  } else {
    convt_tile<DFF, HD>(W2, W2t, bid - NBR - NBC1, Tt);    // W2 [E][DFF][HD] -> [E][HD][DFF]
  }
}

__global__ __launch_bounds__(64) void scan_k(const int* __restrict__ counts,
    int* __restrict__ seg, int* __restrict__ cursor,
    int* __restrict__ ntile, int* __restrict__ tile_e, int* __restrict__ tile_m) {
  if (threadIdx.x == 0) {
    int s = 0, nt = 0;
#pragma unroll
    for (int e = 0; e < NEXP; ++e) {
      seg[e] = s; cursor[e] = s;
      int c = counts[e];
      for (int m = 0; m < c; m += BM) { tile_e[nt] = e; tile_m[nt] = m; ++nt; }
      s += c;
    }
    seg[NEXP] = s;
    ntile[0] = nt;
  }
}

__global__ __launch_bounds__(256) void gather_k(const float* __restrict__ x,
    const int* __restrict__ tok_exp, const float* __restrict__ tok_gate,
    int* __restrict__ cursor, int* __restrict__ perm, float* __restrict__ gatep,
    u16* __restrict__ Xg) {
  const int w = threadIdx.x >> 6, l = threadIdx.x & 63;
  const int t = blockIdx.x * 4 + w;
  int pos = 0;
  if (l == 0) {
    int e = tok_exp[t];
    pos = atomicAdd(&cursor[e], 1);
    perm[pos] = t;
    gatep[pos] = tok_gate[t];
  }
  pos = __shfl(pos, 0);
  const float4* xr = (const float4*)(x + (size_t)t * HD);
  ushort4* dst = (ushort4*)(Xg + (size_t)pos * HD);
#pragma unroll
  for (int i = 0; i < HD / 4 / 64; ++i) {
    float4 v = xr[l + i * 64];
    ushort4 o;
    o.x = f2bf(v.x); o.y = f2bf(v.y); o.z = f2bf(v.z); o.w = f2bf(v.w);
    dst[l + i * 64] = o;
  }
}

// m97-structure grouped GEMM, BK=64 with T21 XOR-swizzled LDS (chunk ^= row&7):
// linear gload_lds dest, pre-swizzled global SOURCE, swizzled frag reads.
// A:[T][KD] bf16 (permuted rows), Bt:[E][ND][KD] bf16.
// EPI 0: H1out = bf16(relu(acc+bias)).   EPI 2: Pt[ks][row][n] = acc (f32, raw partial).
template <int KD, int ND, int EPI, int KSPLIT>
__global__ __launch_bounds__(256, 4) void ffn_gemm(
    const u16* __restrict__ A, const u16* __restrict__ Bt,
    const float* __restrict__ bias, const int* __restrict__ seg,
    const int* __restrict__ ntile, const int* __restrict__ tile_e,
    const int* __restrict__ tile_m,
    u16* __restrict__ H1out, float* __restrict__ Pt) {
  const int bx = blockIdx.x, by = blockIdx.y;
  if (by >= ntile[0]) return;
  const int e  = tile_e[by];
  const int m0 = tile_m[by];
  const int ks = blockIdx.z;
  const int s0 = seg[e];
  const int cnt = seg[e + 1] - s0;
  const int n0 = bx * BN;
  constexpr int NT = (KD / KSPLIT) / BK;
  const int kbase = ks * (KD / KSPLIT);

  __shared__ __align__(16) u16 As[BM * BK];   // [128][64] row-major, XOR-swizzled content
  __shared__ __align__(16) u16 Bs[BN * BK];

  const int t = threadIdx.x;
  const int l = t & 63, w = t >> 6;
  const int wr = w >> 1, wc = w & 1;

  const f32x4 fzero = {0.f, 0.f, 0.f, 0.f};
  f32x4 acc[4][4];
#pragma unroll
  for (int i = 0; i < 4; ++i)
#pragma unroll
    for (int j = 0; j < 4; ++j) acc[i][j] = fzero;

  // Staging: chunk c covers rows [c*32, c*32+32); lane slot idx=c*256+t -> row=idx>>3,
  // 16B-subchunk sub=idx&7. LDS dest linear (idx*16B). Source k-offset pre-swizzled:
  // koff = (sub ^ (row&7)) * 8 elems  (involution; full row still covered -> coalesced).
  const int sub = t & 7, r8 = t >> 3;           // r8 in [0,32)
  const int koff = (sub ^ (r8 & 7)) * 8;
  int aoff[4], boff[4];
  const u16* bte = Bt + (size_t)e * ND * KD;
#pragma unroll
  for (int c = 0; c < 4; ++c) {
    int row = c * 32 + r8;
    int rg = m0 + row; if (rg >= cnt) rg = cnt - 1;
    aoff[c] = (s0 + rg) * KD + kbase + koff;
    boff[c] = (n0 + row) * KD + kbase + koff;
  }

  for (int tt = 0; tt < NT; ++tt) {
    __syncthreads();
    const int ko = tt * BK;
#pragma unroll
    for (int c = 0; c < 4; ++c)
      gload_lds16(A + (size_t)aoff[c] + ko, &As[(c * 256 + t) * 8]);
#pragma unroll
    for (int c = 0; c < 4; ++c)
      gload_lds16(bte + (size_t)boff[c] + ko, &Bs[(c * 256 + t) * 8]);
    __syncthreads();
#pragma unroll
    for (int s = 0; s < 2; ++s) {
      // frag read: chunk index (s*4 + l>>4) ^ (row&7), row&7 == l&7 here
      const int fo = ((s * 4 + (l >> 4)) ^ (l & 7)) * 8;
      s16x8 af[4], bfr[4];
#pragma unroll
      for (int mi = 0; mi < 4; ++mi)
        af[mi] = *(const s16x8*)&As[(wr * 64 + mi * 16 + (l & 15)) * BK + fo];
#pragma unroll
      for (int ni = 0; ni < 4; ++ni)
        bfr[ni] = *(const s16x8*)&Bs[(wc * 64 + ni * 16 + (l & 15)) * BK + fo];
#pragma unroll
      for (int mi = 0; mi < 4; ++mi)
#pragma unroll
        for (int ni = 0; ni < 4; ++ni)
          acc[mi][ni] = __builtin_amdgcn_mfma_f32_16x16x32_bf16(af[mi], bfr[ni], acc[mi][ni], 0, 0, 0);
    }
  }

  // epilogue: C/D frag map col=lane&15, row=(lane>>4)*4+reg  [m89/m91]
  const int lr = (l >> 4) * 4;
  const int lc = l & 15;

  if constexpr (EPI == 0) {
    float bv2[4];
#pragma unroll
    for (int ni = 0; ni < 4; ++ni)
      bv2[ni] = bias[(size_t)e * ND + n0 + wc * 64 + ni * 16 + lc];
#pragma unroll
    for (int mi = 0; mi < 4; ++mi) {
#pragma unroll
      for (int r = 0; r < 4; ++r) {
        int row = m0 + wr * 64 + mi * 16 + lr + r;
        if (row < cnt) {
          u16* hrow = H1out + (size_t)(s0 + row) * ND + n0 + wc * 64;
#pragma unroll
          for (int ni = 0; ni < 4; ++ni) {
            float v = acc[mi][ni][r] + bv2[ni];
            v = v > 0.f ? v : 0.f;
            hrow[ni * 16 + lc] = f2bf(v);
          }
        }
      }
    }
  } else {
    const int totT = seg[NEXP];
#pragma unroll
    for (int mi = 0; mi < 4; ++mi) {
#pragma unroll
      for (int r = 0; r < 4; ++r) {
        int row = m0 + wr * 64 + mi * 16 + lr + r;
        if (row < cnt) {
          float* prow = Pt + ((size_t)ks * totT + s0 + row) * ND + n0 + wc * 64;
#pragma unroll
          for (int ni = 0; ni < 4; ++ni)
            prow[ni * 16 + lc] = acc[mi][ni][r];
        }
      }
    }
  }
}

// out[perm[pos]] = gate[pos] * (b2[e] + sum_ks Pt[ks][pos][:])
__global__ __launch_bounds__(256) void reduce_k(const float* __restrict__ Pt,
    const float* __restrict__ b2, const int* __restrict__ perm,
    const float* __restrict__ gatep, const int* __restrict__ tok_exp,
    float* __restrict__ out) {
  const int pos = blockIdx.x;
  const int totT = gridDim.x;
  const int tok = perm[pos];
  const float g = gatep[pos];
  const int e = tok_exp[tok];
  const int h = threadIdx.x * 4;
  float4 s = *(const float4*)(Pt + ((size_t)0 * totT + pos) * HD + h);
#pragma unroll
  for (int k = 1; k < 4; ++k) {
    float4 p = *(const float4*)(Pt + ((size_t)k * totT + pos) * HD + h);
    s.x += p.x; s.y += p.y; s.z += p.z; s.w += p.w;
  }
  float4 b = *(const float4*)(b2 + (size_t)e * HD + h);
  float4 o;
  o.x = (s.x + b.x) * g; o.y = (s.y + b.y) * g;
  o.z = (s.z + b.z) * g; o.w = (s.w + b.w) * g;
  *(float4*)(out + (size_t)tok * HD + h) = o;
}

extern "C" void kernel_launch(void* const* d_in, const int* in_sizes, int n_in,
                              void* d_out, int out_size, void* d_ws, size_t ws_size,
                              hipStream_t stream) {
  const float* x  = (const float*)d_in[0];
  const float* Wr = (const float*)d_in[1];
  const float* br = (const float*)d_in[2];
  const float* W1 = (const float*)d_in[3];
  const float* b1 = (const float*)d_in[4];
  const float* W2 = (const float*)d_in[5];
  const float* b2 = (const float*)d_in[6];
  float* out = (float*)d_out;

  const int T = in_sizes[0] / HD;   // 4096 tokens
  char* ws = (char*)d_ws;
  int*   counts   = (int*)(ws + 0);
  int*   cursor   = (int*)(ws + 64);
  int*   seg      = (int*)(ws + 128);
  int*   ntile    = (int*)(ws + 192);
  int*   tile_e   = (int*)(ws + 256);
  int*   tile_m   = (int*)(ws + 512);
  int*   tok_exp  = (int*)(ws + 1024);
  float* tok_gate = (float*)(ws + 1024 + 4 * (size_t)T);
  int*   perm     = (int*)(ws + 1024 + 8 * (size_t)T);
  float* gatep    = (float*)(ws + 1024 + 12 * (size_t)T);
  u16*   Xg       = (u16*)(ws + 1024 + 16 * (size_t)T);                       // T*HD bf16 (8MB)
  u16*   H1       = (u16*)(ws + 1024 + 16 * (size_t)T + 2 * (size_t)T * HD);  // T*DFF bf16 (32MB)
  size_t off2     = 1024 + 16 * (size_t)T + 2 * (size_t)T * HD + 2 * (size_t)T * DFF;
  u16*   W1t      = (u16*)(ws + off2);                                        // E*DFF*HD bf16 (64MB)
  u16*   W2t      = (u16*)(ws + off2 + 2 * (size_t)NEXP * HD * DFF);          // E*HD*DFF bf16 (64MB)
  float* Pt       = (float*)W1t;   // GEMM2 split-K partials (4*T*HD f32 = 64MB) reuse W1t

  hipLaunchKernelGGL(zero_k, dim3(1), dim3(64), 0, stream, counts);
  const int NBR = T / 4;
  const int NBC = (HD / 64) * (DFF / 64) * NEXP;   // 8192 per weight
  hipLaunchKernelGGL(prep_k, dim3(NBR + 2 * NBC), dim3(256), 0, stream,
                     x, Wr, br, counts, tok_exp, tok_gate, W1, W1t, W2, W2t, T);
  hipLaunchKernelGGL(scan_k, dim3(1), dim3(64), 0, stream, counts, seg, cursor, ntile, tile_e, tile_m);
  hipLaunchKernelGGL(gather_k, dim3(T / 4), dim3(256), 0, stream,
                     x, tok_exp, tok_gate, cursor, perm, gatep, Xg);
  const int maxtile = (T + BM - 1) / BM + NEXP - 1;   // 39 worst case
  hipLaunchKernelGGL((ffn_gemm<HD, DFF, 0, 1>), dim3(DFF / BN, maxtile, 1), dim3(256), 0, stream,
                     Xg, W1t, b1, seg, ntile, tile_e, tile_m, H1, nullptr);
  hipLaunchKernelGGL((ffn_gemm<DFF, HD, 2, 4>), dim3(HD / BN, maxtile, 4), dim3(256), 0, stream,
                     H1, W2t, nullptr, seg, ntile, tile_e, tile_m, nullptr, Pt);
  hipLaunchKernelGGL(reduce_k, dim3(T), dim3(256), 0, stream, Pt, b2, perm, gatep, tok_exp, out);
}

// Round 8
// 297.168 us; speedup vs baseline: 1.2348x; 1.0384x over previous
//
#include <hip/hip_runtime.h>
#include <stdint.h>

typedef unsigned short u16;
typedef __attribute__((ext_vector_type(8))) short s16x8;   // 8 bf16 in 4 VGPRs
typedef __attribute__((ext_vector_type(4))) float f32x4;   // MFMA accumulator
typedef __attribute__((ext_vector_type(4))) unsigned uint4v;

#define NEXP 8
#define HD 1024
#define DFF 4096
#define BM 128
#define BN 128
#define BK 64     // 128B rows: full-line coalescing; XOR-swizzled LDS (T21 both-sides)

#define CT_S 136  // convt LDS row stride (u16): 272B -> uniform banks for b128 ops

__device__ __forceinline__ u16 f2bf(float f) {
  union { float f; unsigned u; } c; c.f = f;
  unsigned r = c.u + 0x7fffu + ((c.u >> 16) & 1u);   // RNE
  return (u16)(r >> 16);
}

__device__ __forceinline__ unsigned cvtpk(float a, float b) {
  unsigned r;
  asm("v_cvt_pk_bf16_f32 %0, %1, %2" : "=v"(r) : "v"(a), "v"(b));
  return r;   // lo = bf16(a), hi = bf16(b)
}

__device__ __forceinline__ void gload_lds16(const void* g, const void* l) {
  __builtin_amdgcn_global_load_lds(
      (const __attribute__((address_space(1))) unsigned int*)(uintptr_t)g,
      (__attribute__((address_space(3))) unsigned int*)(unsigned)(uintptr_t)l,
      16, 0, 0);
}

__global__ __launch_bounds__(64) void zero_k(int* counts) {
  if (threadIdx.x < NEXP) counts[threadIdx.x] = 0;
}

// 128(k)x64(n) transpose+convert tile: W [K][N] f32 -> Wt [N][K] bf16.
// Phase 1: 8x float4 loads, cvt_pk pack, 4x ds_write_b128 (bank-uniform, data-floor).
// Phase 2: 4x ds_read_b128 + 4x 16B global writes (256B-contiguous per 16 lanes).
template <int K, int N>
__device__ __forceinline__ void convt_tile(const float* __restrict__ W,
    u16* __restrict__ Wt, int idx, u16* __restrict__ T) {
  const int e = idx >> 9;                        // 512 tiles/expert
  const int ti = idx & 511;
  const int k0 = (ti % (K / 128)) * 128;
  const int n0 = (ti / (K / 128)) * 64;
  const float* src = W + (size_t)e * K * N;
  u16* dst = Wt + (size_t)e * K * N;
  const int t = threadIdx.x;
  const int m = t & 15, g = t >> 4;              // nq = m*4, kq = g*8
  const int kq = g * 8, nq = m * 4;
  f32x4 v[8];
#pragma unroll
  for (int i = 0; i < 8; ++i)
    v[i] = *(const f32x4*)(src + (size_t)(k0 + kq + i) * N + n0 + nq);
#pragma unroll
  for (int j = 0; j < 4; ++j) {
    uint4v q;
    q[0] = cvtpk(v[0][j], v[1][j]);
    q[1] = cvtpk(v[2][j], v[3][j]);
    q[2] = cvtpk(v[4][j], v[5][j]);
    q[3] = cvtpk(v[6][j], v[7][j]);
    *(uint4v*)&T[(nq + j) * CT_S + kq] = q;
  }
  __syncthreads();
#pragma unroll
  for (int r = 0; r < 4; ++r) {
    const int nn = r * 16 + g;
    const int c8 = m * 8;
    uint4v q = *(const uint4v*)&T[nn * CT_S + c8];
    *(uint4v*)(dst + (size_t)(n0 + nn) * K + k0 + c8) = q;
  }
}

// prep1: router (4 tokens/block, wave per token) + W1 transpose, one launch.
__global__ __launch_bounds__(256) void prep1_k(
    const float* __restrict__ x, const float* __restrict__ Wr,
    const float* __restrict__ br, int* __restrict__ counts,
    int* __restrict__ tok_exp, float* __restrict__ tok_gate,
    const float* __restrict__ W1, u16* __restrict__ W1t, int T) {
  __shared__ __align__(16) u16 Tt[64 * CT_S];
  const int bid = blockIdx.x;
  const int NBR = T / 4;
  if (bid >= NBR) {
    convt_tile<HD, DFF>(W1, W1t, bid - NBR, Tt);   // W1 [E][HD][DFF] -> [E][DFF][HD]
    return;
  }
  const int w = threadIdx.x >> 6, l = threadIdx.x & 63;
  const int t = bid * 4 + w;
  const float4* xr = (const float4*)(x + (size_t)t * HD);
  float acc[NEXP];
#pragma unroll
  for (int j = 0; j < NEXP; ++j) acc[j] = 0.f;
#pragma unroll
  for (int i = 0; i < 4; ++i) {
    float4 v = xr[l + i * 64];
    const int h = (l + i * 64) * 4;
    const float* w0 = Wr + (size_t)h * NEXP;
#pragma unroll
    for (int c = 0; c < 4; ++c) {
      float xv = (c == 0) ? v.x : (c == 1) ? v.y : (c == 2) ? v.z : v.w;
      const float4* wr4 = (const float4*)(w0 + c * NEXP);
      float4 a = wr4[0], b = wr4[1];
      acc[0] += xv * a.x; acc[1] += xv * a.y; acc[2] += xv * a.z; acc[3] += xv * a.w;
      acc[4] += xv * b.x; acc[5] += xv * b.y; acc[6] += xv * b.z; acc[7] += xv * b.w;
    }
  }
#pragma unroll
  for (int j = 0; j < NEXP; ++j)
#pragma unroll
    for (int off = 32; off > 0; off >>= 1) acc[j] += __shfl_xor(acc[j], off);
  if (l == 0) {
    float lg[NEXP];
    float best = acc[0] + br[0]; int bi = 0;
    lg[0] = best;
#pragma unroll
    for (int j = 1; j < NEXP; ++j) {
      lg[j] = acc[j] + br[j];
      if (lg[j] > best) { best = lg[j]; bi = j; }
    }
    float s = 0.f;
#pragma unroll
    for (int j = 0; j < NEXP; ++j) s += expf(lg[j] - best);
    tok_exp[t] = bi;
    tok_gate[t] = 1.0f / s;
    atomicAdd(&counts[bi], 1);
  }
}

__global__ __launch_bounds__(64) void scan_k(const int* __restrict__ counts,
    int* __restrict__ seg, int* __restrict__ cursor,
    int* __restrict__ ntile, int* __restrict__ tile_e, int* __restrict__ tile_m) {
  if (threadIdx.x == 0) {
    int s = 0, nt = 0;
#pragma unroll
    for (int e = 0; e < NEXP; ++e) {
      seg[e] = s; cursor[e] = s;
      int c = counts[e];
      for (int m = 0; m < c; m += BM) { tile_e[nt] = e; tile_m[nt] = m; ++nt; }
      s += c;
    }
    seg[NEXP] = s;
    ntile[0] = nt;
  }
}

__global__ __launch_bounds__(256) void gather_k(const float* __restrict__ x,
    const int* __restrict__ tok_exp, const float* __restrict__ tok_gate,
    int* __restrict__ cursor, int* __restrict__ perm, float* __restrict__ gatep,
    u16* __restrict__ Xg) {
  const int w = threadIdx.x >> 6, l = threadIdx.x & 63;
  const int t = blockIdx.x * 4 + w;
  int pos = 0;
  if (l == 0) {
    int e = tok_exp[t];
    pos = atomicAdd(&cursor[e], 1);
    perm[pos] = t;
    gatep[pos] = tok_gate[t];
  }
  pos = __shfl(pos, 0);
  const float4* xr = (const float4*)(x + (size_t)t * HD);
  ushort4* dst = (ushort4*)(Xg + (size_t)pos * HD);
#pragma unroll
  for (int i = 0; i < HD / 4 / 64; ++i) {
    float4 v = xr[l + i * 64];
    ushort4 o;
    o.x = f2bf(v.x); o.y = f2bf(v.y); o.z = f2bf(v.z); o.w = f2bf(v.w);
    dst[l + i * 64] = o;
  }
}

// m97-structure grouped GEMM body, BK=64, T21 XOR-swizzled LDS (chunk ^= row&7).
// A:[T][KD] bf16 (permuted rows), Bt:[E][ND][KD] bf16.
// EPI 0: H1out = bf16(relu(acc+bias)).   EPI 2: Pt[ks][row][n] = acc (f32 partial).
template <int KD, int ND, int EPI, int KSPLIT>
__device__ __forceinline__ void gemm_body(
    u16* __restrict__ As, u16* __restrict__ Bs,
    const u16* __restrict__ A, const u16* __restrict__ Bt,
    const float* __restrict__ bias, const int* __restrict__ seg,
    const int* __restrict__ ntile, const int* __restrict__ tile_e,
    const int* __restrict__ tile_m,
    u16* __restrict__ H1out, float* __restrict__ Pt,
    int bx, int by, int ks) {
  if (by >= ntile[0]) return;
  const int e  = tile_e[by];
  const int m0 = tile_m[by];
  const int s0 = seg[e];
  const int cnt = seg[e + 1] - s0;
  const int n0 = bx * BN;
  constexpr int NT = (KD / KSPLIT) / BK;
  const int kbase = ks * (KD / KSPLIT);

  const int t = threadIdx.x;
  const int l = t & 63, w = t >> 6;
  const int wr = w >> 1, wc = w & 1;

  const f32x4 fzero = {0.f, 0.f, 0.f, 0.f};
  f32x4 acc[4][4];
#pragma unroll
  for (int i = 0; i < 4; ++i)
#pragma unroll
    for (int j = 0; j < 4; ++j) acc[i][j] = fzero;

  const int sub = t & 7, r8 = t >> 3;
  const int koff = (sub ^ (r8 & 7)) * 8;
  int aoff[4], boff[4];
  const u16* bte = Bt + (size_t)e * ND * KD;
#pragma unroll
  for (int c = 0; c < 4; ++c) {
    int row = c * 32 + r8;
    int rg = m0 + row; if (rg >= cnt) rg = cnt - 1;
    aoff[c] = (s0 + rg) * KD + kbase + koff;
    boff[c] = (n0 + row) * KD + kbase + koff;
  }

  for (int tt = 0; tt < NT; ++tt) {
    __syncthreads();
    const int ko = tt * BK;
#pragma unroll
    for (int c = 0; c < 4; ++c)
      gload_lds16(A + (size_t)aoff[c] + ko, &As[(c * 256 + t) * 8]);
#pragma unroll
    for (int c = 0; c < 4; ++c)
      gload_lds16(bte + (size_t)boff[c] + ko, &Bs[(c * 256 + t) * 8]);
    __syncthreads();
#pragma unroll
    for (int s = 0; s < 2; ++s) {
      const int fo = ((s * 4 + (l >> 4)) ^ (l & 7)) * 8;
      s16x8 af[4], bfr[4];
#pragma unroll
      for (int mi = 0; mi < 4; ++mi)
        af[mi] = *(const s16x8*)&As[(wr * 64 + mi * 16 + (l & 15)) * BK + fo];
#pragma unroll
      for (int ni = 0; ni < 4; ++ni)
        bfr[ni] = *(const s16x8*)&Bs[(wc * 64 + ni * 16 + (l & 15)) * BK + fo];
#pragma unroll
      for (int mi = 0; mi < 4; ++mi)
#pragma unroll
        for (int ni = 0; ni < 4; ++ni)
          acc[mi][ni] = __builtin_amdgcn_mfma_f32_16x16x32_bf16(af[mi], bfr[ni], acc[mi][ni], 0, 0, 0);
    }
  }

  const int lr = (l >> 4) * 4;
  const int lc = l & 15;

  if constexpr (EPI == 0) {
    float bv2[4];
#pragma unroll
    for (int ni = 0; ni < 4; ++ni)
      bv2[ni] = bias[(size_t)e * ND + n0 + wc * 64 + ni * 16 + lc];
#pragma unroll
    for (int mi = 0; mi < 4; ++mi) {
#pragma unroll
      for (int r = 0; r < 4; ++r) {
        int row = m0 + wr * 64 + mi * 16 + lr + r;
        if (row < cnt) {
          u16* hrow = H1out + (size_t)(s0 + row) * ND + n0 + wc * 64;
#pragma unroll
          for (int ni = 0; ni < 4; ++ni) {
            float v = acc[mi][ni][r] + bv2[ni];
            v = v > 0.f ? v : 0.f;
            hrow[ni * 16 + lc] = f2bf(v);
          }
        }
      }
    }
  } else {
    const int totT = seg[NEXP];
#pragma unroll
    for (int mi = 0; mi < 4; ++mi) {
#pragma unroll
      for (int r = 0; r < 4; ++r) {
        int row = m0 + wr * 64 + mi * 16 + lr + r;
        if (row < cnt) {
          float* prow = Pt + ((size_t)ks * totT + s0 + row) * ND + n0 + wc * 64;
#pragma unroll
          for (int ni = 0; ni < 4; ++ni)
            prow[ni * 16 + lc] = acc[mi][ni][r];
        }
      }
    }
  }
}

// Fused: GEMM1 (blocks [0, ng1)) + W2 transpose (appended blocks).
// W2t is only read by the NEXT launch (gemm2), so completion is guaranteed.
__global__ __launch_bounds__(256, 4) void gemm1_fused_k(
    const u16* __restrict__ Xg, const u16* __restrict__ W1t,
    const float* __restrict__ b1, const int* __restrict__ seg,
    const int* __restrict__ ntile, const int* __restrict__ tile_e,
    const int* __restrict__ tile_m, u16* __restrict__ H1,
    const float* __restrict__ W2, u16* __restrict__ W2t, int ng1) {
  __shared__ __align__(16) u16 sh[2 * BM * BK];   // 32KB; convt uses first 17408B
  const int bid = blockIdx.x;
  if (bid < ng1) {
    gemm_body<HD, DFF, 0, 1>(sh, sh + BM * BK, Xg, W1t, b1, seg, ntile, tile_e,
                             tile_m, H1, nullptr, bid % (DFF / BN), bid / (DFF / BN), 0);
  } else {
    convt_tile<DFF, HD>(W2, W2t, bid - ng1, sh);   // W2 [E][DFF][HD] -> [E][HD][DFF]
  }
}

__global__ __launch_bounds__(256, 4) void gemm2_k(
    const u16* __restrict__ H1, const u16* __restrict__ W2t,
    const int* __restrict__ seg, const int* __restrict__ ntile,
    const int* __restrict__ tile_e, const int* __restrict__ tile_m,
    float* __restrict__ Pt) {
  __shared__ __align__(16) u16 sh[2 * BM * BK];
  gemm_body<DFF, HD, 2, 4>(sh, sh + BM * BK, H1, W2t, nullptr, seg, ntile, tile_e,
                           tile_m, nullptr, Pt, blockIdx.x, blockIdx.y, blockIdx.z);
}

// out[perm[pos]] = gate[pos] * (b2[e] + sum_ks Pt[ks][pos][:])
__global__ __launch_bounds__(256) void reduce_k(const float* __restrict__ Pt,
    const float* __restrict__ b2, const int* __restrict__ perm,
    const float* __restrict__ gatep, const int* __restrict__ tok_exp,
    float* __restrict__ out) {
  const int pos = blockIdx.x;
  const int totT = gridDim.x;
  const int tok = perm[pos];
  const float g = gatep[pos];
  const int e = tok_exp[tok];
  const int h = threadIdx.x * 4;
  float4 s = *(const float4*)(Pt + ((size_t)0 * totT + pos) * HD + h);
#pragma unroll
  for (int k = 1; k < 4; ++k) {
    float4 p = *(const float4*)(Pt + ((size_t)k * totT + pos) * HD + h);
    s.x += p.x; s.y += p.y; s.z += p.z; s.w += p.w;
  }
  float4 b = *(const float4*)(b2 + (size_t)e * HD + h);
  float4 o;
  o.x = (s.x + b.x) * g; o.y = (s.y + b.y) * g;
  o.z = (s.z + b.z) * g; o.w = (s.w + b.w) * g;
  *(float4*)(out + (size_t)tok * HD + h) = o;
}

extern "C" void kernel_launch(void* const* d_in, const int* in_sizes, int n_in,
                              void* d_out, int out_size, void* d_ws, size_t ws_size,
                              hipStream_t stream) {
  const float* x  = (const float*)d_in[0];
  const float* Wr = (const float*)d_in[1];
  const float* br = (const float*)d_in[2];
  const float* W1 = (const float*)d_in[3];
  const float* b1 = (const float*)d_in[4];
  const float* W2 = (const float*)d_in[5];
  const float* b2 = (const float*)d_in[6];
  float* out = (float*)d_out;

  const int T = in_sizes[0] / HD;   // 4096 tokens
  char* ws = (char*)d_ws;
  int*   counts   = (int*)(ws + 0);
  int*   cursor   = (int*)(ws + 64);
  int*   seg      = (int*)(ws + 128);
  int*   ntile    = (int*)(ws + 192);
  int*   tile_e   = (int*)(ws + 256);
  int*   tile_m   = (int*)(ws + 512);
  int*   tok_exp  = (int*)(ws + 1024);
  float* tok_gate = (float*)(ws + 1024 + 4 * (size_t)T);
  int*   perm     = (int*)(ws + 1024 + 8 * (size_t)T);
  float* gatep    = (float*)(ws + 1024 + 12 * (size_t)T);
  u16*   Xg       = (u16*)(ws + 1024 + 16 * (size_t)T);                       // T*HD bf16 (8MB)
  u16*   H1       = (u16*)(ws + 1024 + 16 * (size_t)T + 2 * (size_t)T * HD);  // T*DFF bf16 (32MB)
  size_t off2     = 1024 + 16 * (size_t)T + 2 * (size_t)T * HD + 2 * (size_t)T * DFF;
  u16*   W1t      = (u16*)(ws + off2);                                        // E*DFF*HD bf16 (64MB)
  u16*   W2t      = (u16*)(ws + off2 + 2 * (size_t)NEXP * HD * DFF);          // E*HD*DFF bf16 (64MB)
  float* Pt       = (float*)W1t;   // GEMM2 split-K partials (4*T*HD f32 = 64MB) reuse W1t

  hipLaunchKernelGGL(zero_k, dim3(1), dim3(64), 0, stream, counts);
  const int NBR = T / 4;
  const int NCT = 512 * NEXP;   // 4096 convt tiles per weight
  hipLaunchKernelGGL(prep1_k, dim3(NBR + NCT), dim3(256), 0, stream,
                     x, Wr, br, counts, tok_exp, tok_gate, W1, W1t, T);
  hipLaunchKernelGGL(scan_k, dim3(1), dim3(64), 0, stream, counts, seg, cursor, ntile, tile_e, tile_m);
  hipLaunchKernelGGL(gather_k, dim3(T / 4), dim3(256), 0, stream,
                     x, tok_exp, tok_gate, cursor, perm, gatep, Xg);
  const int maxtile = (T + BM - 1) / BM + NEXP - 1;   // 39 worst case
  const int ng1 = (DFF / BN) * maxtile;               // 1248 GEMM1 blocks
  hipLaunchKernelGGL(gemm1_fused_k, dim3(ng1 + NCT), dim3(256), 0, stream,
                     Xg, W1t, b1, seg, ntile, tile_e, tile_m, H1, W2, W2t, ng1);
  hipLaunchKernelGGL(gemm2_k, dim3(HD / BN, maxtile, 4), dim3(256), 0, stream,
                     H1, W2t, seg, ntile, tile_e, tile_m, Pt);
  hipLaunchKernelGGL(reduce_k, dim3(T), dim3(256), 0, stream, Pt, b2, perm, gatep, tok_exp, out);
}